// Round 3
// baseline (419.060 us; speedup 1.0000x reference)
//
#include <hip/hip_runtime.h>
#include <hip/hip_bf16.h>

typedef unsigned short u16;
typedef unsigned int   u32;

typedef __attribute__((ext_vector_type(8))) short  short8;   // 8 x bf16 (4 VGPRs)
typedef __attribute__((ext_vector_type(4))) float  floatx4;  // MFMA C/D

// round-to-nearest-even pack of two f32 into packed bf16x2 (lo = low u16)
__device__ __forceinline__ u32 rne_pack(float lo, float hi) {
  u32 bl = __float_as_uint(lo), bh = __float_as_uint(hi);
  u32 rl = ((bl + 0x7FFFu + ((bl >> 16) & 1u)) >> 16) & 0xFFFFu;
  u32 rh = (bh + 0x7FFFu + ((bh >> 16) & 1u)) & 0xFFFF0000u;
  return rl | rh;
}

// scale a packed-bf16 x8 msg fragment by w (f32), truncate back to bf16
__device__ __forceinline__ short8 scale_frag(uint4 mraw, float w) {
  const u32* in = (const u32*)&mraw;
  uint4 o; u32* ou = (u32*)&o;
  #pragma unroll
  for (int i = 0; i < 4; ++i) {
    float lo = __uint_as_float(in[i] << 16) * w;
    float hi = __uint_as_float(in[i]) * w;   // low-mantissa noise << bf16 ulp
    ou[i] = __builtin_amdgcn_perm(__float_as_uint(hi), __float_as_uint(lo), 0x07060302u);
  }
  return *(short8*)&o;
}

// ---------------------------------------------------------------------------
// fused: per 256-edge block:
//   A) cluster distances via MFMA (f32 loads -> bf16 frags), student-t ->
//      head-normalize -> mean -> softmax  => w[e][8] in LDS
//   B) z[e] = (w (x) msg) @ W via K=512 MFMA GEMM (W converted+swizzled to
//      LDS per block), atomic f32 scatter into out (pre-bias)
// ---------------------------------------------------------------------------
__global__ __launch_bounds__(256, 2) void fused_kernel(
    const float* __restrict__ msg, const float* __restrict__ xj,
    const float* __restrict__ eij, const float* __restrict__ kc,
    const float* __restrict__ Wg, const int* __restrict__ idx,
    float* __restrict__ out, int E) {
  __shared__ __align__(16) char un[65536];
  float* tl = (float*)un;            // phase A: 256*33 f32 (col 32 = ||x||^2)
  u16*   Wl = (u16*)un;              // phase B: 32768 bf16 = 64 KB swizzled W
  __shared__ __align__(16) float wsm[2048];   // w[256][8]
  __shared__ float kn[32];

  const int tid  = threadIdx.x;
  const int lane = tid & 63, wv = tid >> 6;
  const int ln   = lane & 15, q  = lane >> 4;
  const int e0   = blockIdx.x * 256;

  // ---- A-frags (cluster centers 32x64, f32 -> bf16) + ||k_c||^2 ----
  const float4* kc4 = (const float4*)kc;
  short8 af[2][2];
  float knp[2] = {0.f, 0.f};
  #pragma unroll
  for (int mt = 0; mt < 2; ++mt) {
    #pragma unroll
    for (int kk = 0; kk < 2; ++kk) {
      size_t b4 = (size_t)(mt * 16 + ln) * 16 + kk * 8 + q * 2;
      float4 c0 = kc4[b4], c1 = kc4[b4 + 1];
      knp[mt] += c0.x*c0.x + c0.y*c0.y + c0.z*c0.z + c0.w*c0.w
               + c1.x*c1.x + c1.y*c1.y + c1.z*c1.z + c1.w*c1.w;
      u32 pk[4] = { rne_pack(c0.x, c0.y), rne_pack(c0.z, c0.w),
                    rne_pack(c1.x, c1.y), rne_pack(c1.z, c1.w) };
      af[mt][kk] = *(short8*)pk;
    }
    float s = knp[mt];
    s += __shfl_xor(s, 16);
    s += __shfl_xor(s, 32);
    if (wv == 0 && q == 0) kn[mt * 16 + ln] = s;
  }

  // ---- phase A: dot[c][e] via MFMA; B-frags built from f32 global ----
  const float4* xj4  = (const float4*)xj;
  const float4* eij4 = (const float4*)eij;
  #pragma unroll
  for (int g = 0; g < 4; ++g) {
    int el = wv * 64 + g * 16 + ln;
    int ge = e0 + el; if (ge >= E) ge = 0;   // clamp: finite data, discarded
    size_t b4 = (size_t)ge * 16 + q * 2;
    float4 x0 = xj4[b4],     x1 = xj4[b4 + 1];
    float4 x2 = xj4[b4 + 8], x3 = xj4[b4 + 9];
    float4 ea0 = eij4[b4],     ea1 = eij4[b4 + 1];
    float4 ea2 = eij4[b4 + 8], ea3 = eij4[b4 + 9];
    float s0x = x0.x+ea0.x, s0y = x0.y+ea0.y, s0z = x0.z+ea0.z, s0w = x0.w+ea0.w;
    float s1x = x1.x+ea1.x, s1y = x1.y+ea1.y, s1z = x1.z+ea1.z, s1w = x1.w+ea1.w;
    float s2x = x2.x+ea2.x, s2y = x2.y+ea2.y, s2z = x2.z+ea2.z, s2w = x2.w+ea2.w;
    float s3x = x3.x+ea3.x, s3y = x3.y+ea3.y, s3z = x3.z+ea3.z, s3w = x3.w+ea3.w;
    float ps = s0x*s0x + s0y*s0y + s0z*s0z + s0w*s0w
             + s1x*s1x + s1y*s1y + s1z*s1z + s1w*s1w
             + s2x*s2x + s2y*s2y + s2z*s2z + s2w*s2w
             + s3x*s3x + s3y*s3y + s3z*s3z + s3w*s3w;
    u32 p0[4] = { rne_pack(s0x, s0y), rne_pack(s0z, s0w),
                  rne_pack(s1x, s1y), rne_pack(s1z, s1w) };
    u32 p1[4] = { rne_pack(s2x, s2y), rne_pack(s2z, s2w),
                  rne_pack(s3x, s3y), rne_pack(s3z, s3w) };
    ps += __shfl_xor(ps, 16);   // sum over the 4 k-chunks (q lanes)
    ps += __shfl_xor(ps, 32);
    short8 bb0 = *(short8*)p0, bb1 = *(short8*)p1;
    floatx4 acc0 = {0.f,0.f,0.f,0.f}, acc1 = {0.f,0.f,0.f,0.f};
    acc0 = __builtin_amdgcn_mfma_f32_16x16x32_bf16(af[0][0], bb0, acc0, 0, 0, 0);
    acc0 = __builtin_amdgcn_mfma_f32_16x16x32_bf16(af[0][1], bb1, acc0, 0, 0, 0);
    acc1 = __builtin_amdgcn_mfma_f32_16x16x32_bf16(af[1][0], bb0, acc1, 0, 0, 0);
    acc1 = __builtin_amdgcn_mfma_f32_16x16x32_bf16(af[1][1], bb1, acc1, 0, 0, 0);
    // D: col(edge)=lane&15, row(center)=q*4+i
    #pragma unroll
    for (int i = 0; i < 4; ++i) {
      tl[el * 33 + (q * 4 + i)]      = acc0[i];
      tl[el * 33 + 16 + (q * 4 + i)] = acc1[i];
    }
    if (q == 0) tl[el * 33 + 32] = ps;
  }
  __syncthreads();

  // ---- softmax per edge (one thread per edge) ----
  {
    int e = tid;
    bool valid = (e0 + e) < E;
    float xn = tl[e * 33 + 32];
    float tv[32];
    float hs[4] = {0.f, 0.f, 0.f, 0.f};
    #pragma unroll
    for (int c = 0; c < 32; ++c) {
      float dist = kn[c] + xn - 2.f * tl[e * 33 + c];
      dist = dist > 0.f ? dist : 0.f;
      float t = 1.f / (1.f + dist);          // gamma=1 -> (1+d)^-1
      tv[c] = t;
      hs[c >> 3] += t;
    }
    float r0 = 1.f / hs[0], r1 = 1.f / hs[1], r2 = 1.f / hs[2], r3 = 1.f / hs[3];
    float m[8], mx = -1e30f;
    #pragma unroll
    for (int k = 0; k < 8; ++k) {
      m[k] = 2.5f * (tv[k] * r0 + tv[8 + k] * r1 + tv[16 + k] * r2 + tv[24 + k] * r3);
      mx = m[k] > mx ? m[k] : mx;
    }
    float p[8], sum = 0.f;
    #pragma unroll
    for (int k = 0; k < 8; ++k) { p[k] = __expf(m[k] - mx); sum += p[k]; }
    float rs = valid ? (1.f / sum) : 0.f;    // invalid edges -> w = 0
    floatx4 w0 = {p[0]*rs, p[1]*rs, p[2]*rs, p[3]*rs};
    floatx4 w1 = {p[4]*rs, p[5]*rs, p[6]*rs, p[7]*rs};
    *(floatx4*)&wsm[e * 8]     = w0;
    *(floatx4*)&wsm[e * 8 + 4] = w1;
  }
  __syncthreads();   // all tl reads done before Wl overwrites the union

  // ---- phase B: stage W (f32 -> bf16, swizzled) into LDS ----
  // Wl[((kk*4+q2)*64+n)*8 + j] = bf16(W[(kk*32+q2*8+j)*64 + n])
  #pragma unroll
  for (int it = 0; it < 16; ++it) {
    int c  = (tid >> 6) + it * 4;            // 0..63 = (kk,q2)
    int kk = c >> 2, q2 = c & 3, n = tid & 63;
    const float* src = Wg + (size_t)(kk * 32 + q2 * 8) * 64 + n;
    u32 pk[4];
    #pragma unroll
    for (int jp = 0; jp < 4; ++jp)
      pk[jp] = rne_pack(src[(jp * 2) * 64], src[(jp * 2 + 1) * 64]);
    *(uint4*)&Wl[(c * 64 + n) * 8] = *(uint4*)pk;
  }

  // msg fragments (f32 -> packed bf16) and w rows
  const float4* msg4 = (const float4*)msg;
  uint4 mf[4][2];
  const int edgebase = e0 + wv * 64;
  #pragma unroll
  for (int s = 0; s < 4; ++s) {
    int eg = edgebase + s * 16 + ln; if (eg >= E) eg = E - 1;
    size_t mb = (size_t)eg * 16 + q * 2;
    #pragma unroll
    for (int h = 0; h < 2; ++h) {
      float4 m0 = msg4[mb + h * 8], m1 = msg4[mb + h * 8 + 1];
      u32 pk[4] = { rne_pack(m0.x, m0.y), rne_pack(m0.z, m0.w),
                    rne_pack(m1.x, m1.y), rne_pack(m1.z, m1.w) };
      mf[s][h] = *(uint4*)pk;
    }
  }
  floatx4 wf[4][2];
  #pragma unroll
  for (int s = 0; s < 4; ++s) {
    int eL = wv * 64 + s * 16 + ln;
    wf[s][0] = *(floatx4*)&wsm[eL * 8];
    wf[s][1] = *(floatx4*)&wsm[eL * 8 + 4];
  }
  floatx4 acc[4][4];
  #pragma unroll
  for (int s = 0; s < 4; ++s)
    #pragma unroll
    for (int t = 0; t < 4; ++t) { floatx4 z = {0.f,0.f,0.f,0.f}; acc[s][t] = z; }
  __syncthreads();

  // K-loop: 8 clusters x 2 half-rows of 32 — no barriers inside
  #pragma unroll
  for (int kb = 0; kb < 8; ++kb) {
    float wsc[4];
    #pragma unroll
    for (int s = 0; s < 4; ++s) wsc[s] = wf[s][kb >> 2][kb & 3];
    #pragma unroll
    for (int hh = 0; hh < 2; ++hh) {
      int kk = kb * 2 + hh;
      short8 bfr[4];
      #pragma unroll
      for (int t = 0; t < 4; ++t)
        bfr[t] = *(short8*)&Wl[((kk * 4 + q) * 64 + t * 16 + ln) * 8];
      #pragma unroll
      for (int s = 0; s < 4; ++s) {
        short8 a = scale_frag(mf[s][hh], wsc[s]);
        #pragma unroll
        for (int t = 0; t < 4; ++t)
          acc[s][t] = __builtin_amdgcn_mfma_f32_16x16x32_bf16(a, bfr[t], acc[s][t], 0, 0, 0);
      }
    }
  }

  // ---- epilogue: f32 atomic scatter (D row=q*4+i -> edge, col=t*16+ln) ----
  #pragma unroll
  for (int s = 0; s < 4; ++s) {
    #pragma unroll
    for (int i = 0; i < 4; ++i) {
      int eg = edgebase + s * 16 + q * 4 + i;
      if (eg < E) {
        int node = idx[eg];
        float* dst = &out[(size_t)node * 64 + ln];
        #pragma unroll
        for (int t = 0; t < 4; ++t) unsafeAtomicAdd(dst + t * 16, acc[s][t][i]);
      }
    }
  }
}

// ---------------------------------------------------------------------------
// finish: out = leaky_relu(out + b) in place (f32)
// ---------------------------------------------------------------------------
__global__ __launch_bounds__(256) void finish_kernel(
    float* __restrict__ out, const float* __restrict__ b, int n4) {
  int i = blockIdx.x * 256 + threadIdx.x;
  if (i >= n4) return;
  float4 v = ((const float4*)out)[i];
  int cb = (i & 15) * 4;
  v.x += b[cb];     v.x = v.x > 0.f ? v.x : 0.01f * v.x;
  v.y += b[cb + 1]; v.y = v.y > 0.f ? v.y : 0.01f * v.y;
  v.z += b[cb + 2]; v.z = v.z > 0.f ? v.z : 0.01f * v.z;
  v.w += b[cb + 3]; v.w = v.w > 0.f ? v.w : 0.01f * v.w;
  ((float4*)out)[i] = v;
}

// ---------------------------------------------------------------------------
extern "C" void kernel_launch(void* const* d_in, const int* in_sizes, int n_in,
                              void* d_out, int out_size, void* d_ws, size_t ws_size,
                              hipStream_t stream) {
  // inputs (all f32 except index/num_nodes): 0 msg, 1 x_i (unused), 2 x_j,
  // 3 e_ij, 4 index (i32), 5 num_nodes, 6 k[4][8][64], 7 W[512][64], 8 b[64]
  const float* msg = (const float*)d_in[0];
  const float* xj  = (const float*)d_in[2];
  const float* eij = (const float*)d_in[3];
  const int*   idx = (const int*)d_in[4];
  const float* kc  = (const float*)d_in[6];
  const float* Wg  = (const float*)d_in[7];
  const float* bg  = (const float*)d_in[8];

  int E    = in_sizes[0] / 64;
  int Nout = out_size;                       // num_nodes * 64
  float* out = (float*)d_out;

  hipMemsetAsync(out, 0, (size_t)Nout * 4, stream);

  int blocks = (E + 255) / 256;
  fused_kernel<<<blocks, 256, 0, stream>>>(msg, xj, eij, kc, Wg, idx, out, E);

  int n4 = Nout / 4;
  finish_kernel<<<(n4 + 255) / 256, 256, 0, stream>>>(out, bg, n4);
}